// Round 5
// baseline (260.637 us; speedup 1.0000x reference)
//
#include <hip/hip_runtime.h>
#include <hip/hip_bf16.h>

// 2-layer GCN: out = A_hat @ relu((A_hat@X)@W1 + b1) @ W2 + b2,  A_hat = D^-1/2 (A+I) D^-1/2
// R8-R12 post-mortem: gemm12 pinned at 44-56us across 5 structures. Unifying diagnosis:
//   hipcc will NOT keep large long-lived weight-fragment arrays in VGPRs across the row
//   loop (VGPR_Count=52 in R11/R12 despite 64+ VGPRs of "persistent" frags -> spilled;
//   R0/R9/R10 paid the same cost as per-iteration L2 weight loads). Every round had
//   ~50-70 serialized loads/wave-iter ~= 10K cyc/iter -> ~44-56us, invariant to
//   occupancy, block count, and weight L2 traffic.
// R13: feed MFMA B-operands DIRECTLY from LDS each use -- nothing to spill. Weights in
//   fragment-order LDS: chunk(wave,tile,kfrag) = contiguous 64-lane x 16B, in-loop read
//   is ds_read_b128 at uniform-base + lane*16 (zero conflicts, ~11cyc). W1 64KB + W2
//   64KB + h2s 8.25KB = 139.3KB LDS, 1 block/CU, 256 blocks x 512thr. Per-iter VMEM:
//   4 Y-loads + 4 stores/lane. Staged from 16x replicas (prologue, unique lines).

static constexpr int N_NODES = 50000;
static constexpr int N_EDGES = 800000;
static constexpr int F_IN = 128;
static constexpr int HID  = 256;
static constexpr int F_OUT = 128;
static constexpr int H2P  = 258;   // h2s pitch (shorts): 129 dwords == 1 mod 32 banks
static constexpr int NREP = 16;    // weight replicas (L2 spread for staging reads)

typedef __attribute__((ext_vector_type(8))) short short8;   // 8 bf16 raw bits (4 VGPRs)
typedef __attribute__((ext_vector_type(4))) float f32x4;

__device__ __forceinline__ unsigned short f2bf(float f) {   // RNE fp32->bf16
    union { float f; unsigned u; } x; x.f = f;
    unsigned r = x.u + 0x7FFF + ((x.u >> 16) & 1);
    return (unsigned short)(r >> 16);
}
__device__ __forceinline__ float bf2f(unsigned short h) {
    union { unsigned u; float f; } x; x.u = ((unsigned)h) << 16;
    return x.f;
}

// Fused independent prep: deg/pos atomics  |  W1^T x16  |  W2^T x16   (grid-partitioned)
__global__ void deg_wt_kernel(const int* __restrict__ dst, int* __restrict__ deg,
                              int* __restrict__ pos, int E,
                              const float* __restrict__ W1, unsigned short* __restrict__ w1t,
                              const float* __restrict__ W2, unsigned short* __restrict__ w2t,
                              int EB, int NB1) {
    const int b = blockIdx.x;
    if (b < EB) {
        int i = b * 256 + threadIdx.x;
        if (i < E) pos[i] = atomicAdd(&deg[dst[i]], 1);
    } else if (b < EB + NB1) {
        int t = (b - EB) * 256 + threadIdx.x;       // W1: F_IN rows x HID cols -> w1t[HID][F_IN]
        if (t < F_IN * HID) {
            int n = t / F_IN, k = t - n * F_IN;
            unsigned short v = f2bf(W1[(size_t)k * HID + n]);
#pragma unroll
            for (int r = 0; r < NREP; r++) w1t[(size_t)r * F_IN * HID + t] = v;
        }
    } else {
        int t = (b - EB - NB1) * 256 + threadIdx.x; // W2: HID rows x F_OUT cols -> w2t[F_OUT][HID]
        if (t < HID * F_OUT) {
            int n = t / HID, k = t - n * HID;
            unsigned short v = f2bf(W2[(size_t)k * F_OUT + n]);
#pragma unroll
            for (int r = 0; r < NREP; r++) w2t[(size_t)r * HID * F_OUT + t] = v;
        }
    }
}

// Fused: per-block sum of deg -> bsums, plus dinv[i] = rsqrt(deg+1).
__global__ __launch_bounds__(256) void scan_reduce_dinv(const int* __restrict__ deg,
                                                        int* __restrict__ bsums,
                                                        float* __restrict__ dinv, int N) {
    int i = blockIdx.x * 256 + threadIdx.x;
    int v = (i < N) ? deg[i] : 0;
    if (i < N) dinv[i] = rsqrtf((float)(v + 1));   // +1 = self loop
#pragma unroll
    for (int ofs = 32; ofs > 0; ofs >>= 1) v += __shfl_down(v, ofs);
    __shared__ int ws[4];
    if ((threadIdx.x & 63) == 0) ws[threadIdx.x >> 6] = v;
    __syncthreads();
    if (threadIdx.x == 0) bsums[blockIdx.x] = ws[0] + ws[1] + ws[2] + ws[3];
}

// Fused: blocks [0,nb): redundant LDS scan of bsums + intra-block scan of deg -> off;
// blocks [nb, ...): xs = bf16(dinv * x)  (dinv ready since scan_reduce_dinv).
__global__ __launch_bounds__(256) void scan_final_scalex(const int* __restrict__ deg,
                                                         const int* __restrict__ bsums,
                                                         int* __restrict__ off, int N, int nb,
                                                         const float* __restrict__ x,
                                                         const float* __restrict__ dinv,
                                                         unsigned short* __restrict__ xs) {
    const int tid = threadIdx.x;
    if ((int)blockIdx.x >= nb) {   // scalex partition
        int i = (blockIdx.x - nb) * 256 + tid;     // one thread per 8 elems
        if (i < N_NODES * F_IN / 8) {
            float dv = dinv[i >> 4];
            float4 v0 = ((const float4*)x)[i * 2];
            float4 v1 = ((const float4*)x)[i * 2 + 1];
            short8 o;
            o[0] = (short)f2bf(v0.x * dv); o[1] = (short)f2bf(v0.y * dv);
            o[2] = (short)f2bf(v0.z * dv); o[3] = (short)f2bf(v0.w * dv);
            o[4] = (short)f2bf(v1.x * dv); o[5] = (short)f2bf(v1.y * dv);
            o[6] = (short)f2bf(v1.z * dv); o[7] = (short)f2bf(v1.w * dv);
            *(short8*)(xs + (size_t)i * 8) = o;
        }
        return;
    }
    __shared__ int bs[256];
    __shared__ int s[256];
    bs[tid] = (tid < nb) ? bsums[tid] : 0;
    const int i = blockIdx.x * 256 + tid;
    int v = (i < N) ? deg[i] : 0;
    s[tid] = v;
    __syncthreads();
    for (int ofs = 1; ofs < 256; ofs <<= 1) {
        int tb = (tid >= ofs) ? bs[tid - ofs] : 0;
        int tv = (tid >= ofs) ? s[tid - ofs] : 0;
        __syncthreads();
        bs[tid] += tb;
        s[tid] += tv;
        __syncthreads();
    }
    int bbase = (blockIdx.x == 0) ? 0 : bs[blockIdx.x - 1];
    int excl = (tid == 0) ? 0 : s[tid - 1];
    if (i <= N) off[i] = bbase + excl;
}

// Pure scatter: csr[off[dst] + pos] = src.  No atomics.
__global__ void scatter_kernel(const int* __restrict__ src, const int* __restrict__ dst,
                               const int* __restrict__ pos, const int* __restrict__ off,
                               int* __restrict__ csr, int E) {
    int i = blockIdx.x * blockDim.x + threadIdx.x;
    if (i < E) csr[off[dst[i]] + pos[i]] = src[i];
}

// Wave-per-node aggregation over 128-dim bf16 rows, fp32 accumulate.
// Wave = 4 edge-slots x 16 lanes (ushort8 / 16 B per lane); 4 nodes per 256-block.
// MODE 0: out_bf16[n] = bf16( dinv[n] * (self + sum) )
// MODE 1: out_f32[n]  = dinv[n] * (self + sum) + bias
template <int MODE>
__global__ __launch_bounds__(256) void agg_bf16(const unsigned short* __restrict__ hs,
                                                const int* __restrict__ off,
                                                const int* __restrict__ csr,
                                                const float* __restrict__ dinv,
                                                const float* __restrict__ bias,
                                                void* __restrict__ outp, int N) {
    const int wid = threadIdx.x >> 6;
    const int n = blockIdx.x * 4 + wid;
    if (n >= N) return;
    const int lane = threadIdx.x & 63;
    const int lane16 = lane & 15;
    const int slot = lane >> 4;   // 0..3

    float va[8], vb[8], vc[8], vd[8];
#pragma unroll
    for (int j = 0; j < 8; j++) { va[j] = 0.f; vb[j] = 0.f; vc[j] = 0.f; vd[j] = 0.f; }

    if (slot == 0) {  // self loop
        short8 s = *(const short8*)(hs + (size_t)n * 128 + lane16 * 8);
#pragma unroll
        for (int j = 0; j < 8; j++) va[j] = bf2f((unsigned short)s[j]);
    }

    const int e0 = off[n];
    const int e1 = off[n + 1];
    for (int e = e0 + slot; e < e1; e += 16) {
        const int i1 = e + 4, i2 = e + 8, i3 = e + 12;
        const float f1 = (i1 < e1) ? 1.f : 0.f;
        const float f2 = (i2 < e1) ? 1.f : 0.f;
        const float f3 = (i3 < e1) ? 1.f : 0.f;
        const int c1 = min(i1, e1 - 1), c2 = min(i2, e1 - 1), c3 = min(i3, e1 - 1);
        int s0 = csr[e];
        int s1 = csr[c1];
        int s2 = csr[c2];
        int s3 = csr[c3];
        short8 v0 = *(const short8*)(hs + (size_t)s0 * 128 + lane16 * 8);
        short8 v1 = *(const short8*)(hs + (size_t)s1 * 128 + lane16 * 8);
        short8 v2 = *(const short8*)(hs + (size_t)s2 * 128 + lane16 * 8);
        short8 v3 = *(const short8*)(hs + (size_t)s3 * 128 + lane16 * 8);
#pragma unroll
        for (int j = 0; j < 8; j++) va[j] += bf2f((unsigned short)v0[j]);
#pragma unroll
        for (int j = 0; j < 8; j++) vb[j] = fmaf(f1, bf2f((unsigned short)v1[j]), vb[j]);
#pragma unroll
        for (int j = 0; j < 8; j++) vc[j] = fmaf(f2, bf2f((unsigned short)v2[j]), vc[j]);
#pragma unroll
        for (int j = 0; j < 8; j++) vd[j] = fmaf(f3, bf2f((unsigned short)v3[j]), vd[j]);
    }
#pragma unroll
    for (int j = 0; j < 8; j++) va[j] += vb[j] + vc[j] + vd[j];

#pragma unroll
    for (int j = 0; j < 8; j++) va[j] += __shfl_down(va[j], 32);
#pragma unroll
    for (int j = 0; j < 8; j++) va[j] += __shfl_down(va[j], 16);

    if (lane < 16) {
        float dv = dinv[n];
        if (MODE == 0) {
            short8 o;
#pragma unroll
            for (int j = 0; j < 8; j++) o[j] = (short)f2bf(va[j] * dv);
            *(short8*)((unsigned short*)outp + (size_t)n * 128 + lane * 8) = o;
        } else {
            float* op = (float*)outp + (size_t)n * 128 + lane * 8;
            float4 o0, o1;
            o0.x = va[0] * dv + bias[lane * 8 + 0];
            o0.y = va[1] * dv + bias[lane * 8 + 1];
            o0.z = va[2] * dv + bias[lane * 8 + 2];
            o0.w = va[3] * dv + bias[lane * 8 + 3];
            o1.x = va[4] * dv + bias[lane * 8 + 4];
            o1.y = va[5] * dv + bias[lane * 8 + 5];
            o1.z = va[6] * dv + bias[lane * 8 + 6];
            o1.w = va[7] * dv + bias[lane * 8 + 7];
            ((float4*)op)[0] = o0;
            ((float4*)op)[1] = o1;
        }
    }
}

// Fused double GEMM, LDS-fed weights: hs2 = dinv * ( relu(Y@W1 + b1) @ W2 ).
// 256 blocks x 512 thr (8 waves), 1 block/CU (139.3KB LDS). Prologue stages W1,W2 into
// FRAGMENT-ORDER LDS from replica (blockIdx&15): chunk(wid,[t,]c) = 64 lanes x 16B where
// lane l holds the short8 that wave wid's lane l consumes as its MFMA B-operand -- the
// in-loop read is ds_read_b128 at uniform-base + lane*16: linear, conflict-free. Nothing
// persistent in VGPRs -> no spills (the R11/R12 failure). Main loop per 16-row tile:
// 4 Y-loads -> 8 ds(B1) + 8 MFMA -> relu/bf16 -> h2s[16][258] -> barrier ->
// 8 ds(h) + 8 ds(B2) + 8 MFMA -> *dinv -> store -> barrier.
// Frag layouts: A/B m(n)=lane&15, k=q*8+j;  D col=lane&15, row=q*4+reg.
__global__ __launch_bounds__(512, 2) void gemm12(const unsigned short* __restrict__ Y,
                                                 const unsigned short* __restrict__ w1t,
                                                 const float* __restrict__ b1,
                                                 const unsigned short* __restrict__ w2t,
                                                 const float* __restrict__ dinv,
                                                 unsigned short* __restrict__ hs2, int M) {
    __shared__ unsigned short w1l[F_IN * HID];    // 65536 B, fragment-order
    __shared__ unsigned short w2l[HID * F_OUT];   // 65536 B, fragment-order
    __shared__ unsigned short h2s[16 * H2P];      // 8256 B

    const int tid = threadIdx.x;
    const int wid = tid >> 6;   // 0..7
    const int lane = tid & 63;
    const int an = lane & 15;
    const int q = lane >> 4;
    const int rep = blockIdx.x & (NREP - 1);

    // ---- stage weights into fragment-order LDS (linear ds_write, strided L2 reads) ----
    {
        const unsigned short* w1r = w1t + (size_t)rep * F_IN * HID;
        const unsigned short* w2r = w2t + (size_t)rep * HID * F_OUT;
        // W1 chunks: id = wid*8 + t*4 + c; lane l holds w1^T[col=wid*32+t*16+(l&15)][k=(l>>4)*8+c*32 ..]
        for (int i = tid; i < 4096; i += 512) {
            const int cw = i >> 9;
            const int t  = (i >> 8) & 1;
            const int c  = (i >> 6) & 3;
            const int l  = i & 63;
            const int col = cw * 32 + t * 16 + (l & 15);
            const int off = col * F_IN + (l >> 4) * 8 + c * 32;
            *(short8*)(w1l + (size_t)i * 8) = *(const short8*)(w1r + off);
        }
        // W2 chunks: id = wid*8 + c; lane l holds w2^T[col=wid*16+(l&15)][k=(l>>4)*8+c*32 ..]
        for (int i = tid; i < 4096; i += 512) {
            const int cw = i >> 9;
            const int c  = (i >> 6) & 7;
            const int l  = i & 63;
            const int colB = cw * 16 + (l & 15);
            const int off = colB * HID + (l >> 4) * 8 + c * 32;
            *(short8*)(w2l + (size_t)i * 8) = *(const short8*)(w2r + off);
        }
    }
    float bv0 = b1[wid * 32 + an];
    float bv1 = b1[wid * 32 + 16 + an];
    __syncthreads();

    const int T = M >> 4;   // 3125 row tiles, exact (50000 = 16*3125)
    for (int t0 = blockIdx.x; t0 < T; t0 += gridDim.x) {
        const int m0 = t0 * 16;

        // ---- Phase A: h2 = relu(Y@W1+b1) -> LDS (wave wid: cols [wid*32, wid*32+32)) ----
        short8 a[4];
        {
            const unsigned short* yp = Y + (size_t)(m0 + an) * F_IN + q * 8;
#pragma unroll
            for (int c = 0; c < 4; c++) a[c] = *(const short8*)(yp + c * 32);
        }
        f32x4 accA0 = {0.f, 0.f, 0.f, 0.f};
        f32x4 accA1 = {0.f, 0.f, 0.f, 0.f};
#pragma unroll
        for (int c = 0; c < 4; c++) {
            const short8 b0 = *(const short8*)(w1l + ((size_t)((wid * 8 + c) * 64 + lane)) * 8);
            const short8 b1f = *(const short8*)(w1l + ((size_t)((wid * 8 + 4 + c) * 64 + lane)) * 8);
            accA0 = __builtin_amdgcn_mfma_f32_16x16x32_bf16(a[c], b0, accA0, 0, 0, 0);
            accA1 = __builtin_amdgcn_mfma_f32_16x16x32_bf16(a[c], b1f, accA1, 0, 0, 0);
        }
        {
            const int c0 = wid * 32 + an;
            unsigned short* hrow = &h2s[(q * 4) * H2P];
#pragma unroll
            for (int rr = 0; rr < 4; rr++) {
                hrow[rr * H2P + c0]      = f2bf(fmaxf(accA0[rr] + bv0, 0.f));
                hrow[rr * H2P + c0 + 16] = f2bf(fmaxf(accA1[rr] + bv1, 0.f));
            }
        }
        __syncthreads();

        // ---- Phase B: hs2 = dinv * (h2 @ W2)  (wave wid: cols [wid*16, wid*16+16)) ----
        {
            short8 h[8];
            const unsigned short* hp = &h2s[an * H2P + q * 8];
#pragma unroll
            for (int c = 0; c < 8; c++) h[c] = *(const short8*)(hp + c * 32);
            f32x4 acc = {0.f, 0.f, 0.f, 0.f};
#pragma unroll
            for (int c = 0; c < 8; c++) {
                const short8 b2f = *(const short8*)(w2l + ((size_t)((wid * 8 + c) * 64 + lane)) * 8);
                acc = __builtin_amdgcn_mfma_f32_16x16x32_bf16(h[c], b2f, acc, 0, 0, 0);
            }
            const float4 dv4 = ((const float4*)dinv)[(m0 >> 2) + q];
            unsigned short* op = hs2 + (size_t)(m0 + q * 4) * F_OUT + wid * 16 + an;
            op[0]         = f2bf(acc[0] * dv4.x);
            op[F_OUT]     = f2bf(acc[1] * dv4.y);
            op[2 * F_OUT] = f2bf(acc[2] * dv4.z);
            op[3 * F_OUT] = f2bf(acc[3] * dv4.w);
        }
        __syncthreads();
    }
}

extern "C" void kernel_launch(void* const* d_in, const int* in_sizes, int n_in,
                              void* d_out, int out_size, void* d_ws, size_t ws_size,
                              hipStream_t stream) {
    const float* x  = (const float*)d_in[0];
    const int*   ei = (const int*)d_in[1];   // [2,E] int32
    const float* W1 = (const float*)d_in[2];
    const float* b1 = (const float*)d_in[3];
    const float* W2 = (const float*)d_in[4];
    const float* b2 = (const float*)d_in[5];

    const int N = N_NODES;
    const int E = N_EDGES;
    const int* srcp = ei;
    const int* dstp = ei + E;

    char* base = (char*)d_ws;
    size_t o = 0;
    auto alloc = [&](size_t bytes) {
        void* p = base + o;
        o = (o + bytes + 255) & ~(size_t)255;
        return p;
    };
    int*            deg  = (int*)alloc((size_t)N * 4);
    int*            offs = (int*)alloc((size_t)(N + 1) * 4);
    float*          dinv = (float*)alloc((size_t)N * 4);
    int*            bsum = (int*)alloc(256 * 4);
    int*            pos  = (int*)alloc((size_t)E * 4);
    int*            csr  = (int*)alloc((size_t)E * 4);
    unsigned short* xs   = (unsigned short*)alloc((size_t)N * F_IN * 2);  // dinv*x, bf16
    unsigned short* Y    = (unsigned short*)alloc((size_t)N * F_IN * 2);  // A_hat@X, bf16
    unsigned short* w1t  = (unsigned short*)alloc((size_t)NREP * F_IN * HID * 2);
    unsigned short* w2t  = (unsigned short*)alloc((size_t)NREP * HID * F_OUT * 2);
    unsigned short* hs2  = xs;  // xs dead after agg1

    hipMemsetAsync(deg, 0, (size_t)N * 4, stream);

    const int NB  = (N + 256) / 256;           // 196, covers i==N in scan_final
    const int NBX = (N * F_IN / 8 + 255) / 256;
    const int EB  = (E + 255) / 256;
    const int NB1 = (F_IN * HID + 255) / 256;
    const int NB2 = (HID * F_OUT + 255) / 256;

    deg_wt_kernel<<<EB + NB1 + NB2, 256, 0, stream>>>(dstp, deg, pos, E, W1, w1t, W2, w2t, EB, NB1);
    scan_reduce_dinv<<<NB, 256, 0, stream>>>(deg, bsum, dinv, N);
    scan_final_scalex<<<NB + NBX, 256, 0, stream>>>(deg, bsum, offs, N, NB, x, dinv, xs);
    scatter_kernel<<<EB, 256, 0, stream>>>(srcp, dstp, pos, offs, csr, E);

    // layer 1 agg: Y = A_hat@X (bf16 gather)
    agg_bf16<0><<<(N + 3) / 4, 256, 0, stream>>>(xs, offs, csr, dinv, nullptr, Y, N);
    // fused GEMMs: hs2 = dinv * ( relu(Y@W1+b1) @ W2 ), LDS-fed fragment-order weights
    gemm12<<<256, 512, 0, stream>>>(Y, w1t, b1, w2t, dinv, hs2, N);
    // layer 2 agg: out = dinv*(hs2[self]+gather) + b2
    agg_bf16<1><<<(N + 3) / 4, 256, 0, stream>>>(hs2, offs, csr, dinv, b2, d_out, N);
}

// Round 6
// 247.698 us; speedup vs baseline: 1.0522x; 1.0522x over previous
//
#include <hip/hip_runtime.h>
#include <hip/hip_bf16.h>

// 2-layer GCN: out = A_hat @ relu((A_hat@X)@W1 + b1) @ W2 + b2,  A_hat = D^-1/2 (A+I) D^-1/2
// R8-R13 post-mortem: gemm12 pinned at 44-56us across 6 structures (per-tile L2 loads,
//   dbuf, 2x TLP, persistent regs, replicas, LDS-fed frags). All pipes <6% busy, runtime
//   ~10.7K cyc/CU/iteration vs ~3-4K visible work. Shared invariant: 16-row tile per
//   barrier-pair -> per-iteration fixed costs (Y-load latency exposed once/iter, 2 full
//   vmcnt(0)+lgkmcnt(0) barrier drains with the whole block lockstepped, loop overhead)
//   dominate 4x over useful work.
// R14: 64-row macro-tile per barrier-pair. 16 Y-loads in flight together; each W1/W2
//   fragment ds_read feeds 4 MFMAs; 32+32 MFMA between barriers; 2 barriers/64 rows
//   (was 8); <=4 iterations/block (was 12.2). h2s = [64][256] XOR-swizzled
//   (byte ^= (row&7)<<4, conflict-free phase-B reads) so LDS = 64K+64K+32K = 160KiB.
//   Fragment layouts identical to R13 (verified).

static constexpr int N_NODES = 50000;
static constexpr int N_EDGES = 800000;
static constexpr int F_IN = 128;
static constexpr int HID  = 256;
static constexpr int F_OUT = 128;
static constexpr int NREP = 16;    // weight replicas (L2 spread for staging reads)

typedef __attribute__((ext_vector_type(8))) short short8;   // 8 bf16 raw bits (4 VGPRs)
typedef __attribute__((ext_vector_type(4))) float f32x4;

__device__ __forceinline__ unsigned short f2bf(float f) {   // RNE fp32->bf16
    union { float f; unsigned u; } x; x.f = f;
    unsigned r = x.u + 0x7FFF + ((x.u >> 16) & 1);
    return (unsigned short)(r >> 16);
}
__device__ __forceinline__ float bf2f(unsigned short h) {
    union { unsigned u; float f; } x; x.u = ((unsigned)h) << 16;
    return x.f;
}

// Fused independent prep: deg/pos atomics  |  W1^T x16  |  W2^T x16   (grid-partitioned)
__global__ void deg_wt_kernel(const int* __restrict__ dst, int* __restrict__ deg,
                              int* __restrict__ pos, int E,
                              const float* __restrict__ W1, unsigned short* __restrict__ w1t,
                              const float* __restrict__ W2, unsigned short* __restrict__ w2t,
                              int EB, int NB1) {
    const int b = blockIdx.x;
    if (b < EB) {
        int i = b * 256 + threadIdx.x;
        if (i < E) pos[i] = atomicAdd(&deg[dst[i]], 1);
    } else if (b < EB + NB1) {
        int t = (b - EB) * 256 + threadIdx.x;       // W1: F_IN rows x HID cols -> w1t[HID][F_IN]
        if (t < F_IN * HID) {
            int n = t / F_IN, k = t - n * F_IN;
            unsigned short v = f2bf(W1[(size_t)k * HID + n]);
#pragma unroll
            for (int r = 0; r < NREP; r++) w1t[(size_t)r * F_IN * HID + t] = v;
        }
    } else {
        int t = (b - EB - NB1) * 256 + threadIdx.x; // W2: HID rows x F_OUT cols -> w2t[F_OUT][HID]
        if (t < HID * F_OUT) {
            int n = t / HID, k = t - n * HID;
            unsigned short v = f2bf(W2[(size_t)k * F_OUT + n]);
#pragma unroll
            for (int r = 0; r < NREP; r++) w2t[(size_t)r * HID * F_OUT + t] = v;
        }
    }
}

// Fused: per-block sum of deg -> bsums, plus dinv[i] = rsqrt(deg+1).
__global__ __launch_bounds__(256) void scan_reduce_dinv(const int* __restrict__ deg,
                                                        int* __restrict__ bsums,
                                                        float* __restrict__ dinv, int N) {
    int i = blockIdx.x * 256 + threadIdx.x;
    int v = (i < N) ? deg[i] : 0;
    if (i < N) dinv[i] = rsqrtf((float)(v + 1));   // +1 = self loop
#pragma unroll
    for (int ofs = 32; ofs > 0; ofs >>= 1) v += __shfl_down(v, ofs);
    __shared__ int ws[4];
    if ((threadIdx.x & 63) == 0) ws[threadIdx.x >> 6] = v;
    __syncthreads();
    if (threadIdx.x == 0) bsums[blockIdx.x] = ws[0] + ws[1] + ws[2] + ws[3];
}

// Fused: blocks [0,nb): redundant LDS scan of bsums + intra-block scan of deg -> off;
// blocks [nb, ...): xs = bf16(dinv * x)  (dinv ready since scan_reduce_dinv).
__global__ __launch_bounds__(256) void scan_final_scalex(const int* __restrict__ deg,
                                                         const int* __restrict__ bsums,
                                                         int* __restrict__ off, int N, int nb,
                                                         const float* __restrict__ x,
                                                         const float* __restrict__ dinv,
                                                         unsigned short* __restrict__ xs) {
    const int tid = threadIdx.x;
    if ((int)blockIdx.x >= nb) {   // scalex partition
        int i = (blockIdx.x - nb) * 256 + tid;     // one thread per 8 elems
        if (i < N_NODES * F_IN / 8) {
            float dv = dinv[i >> 4];
            float4 v0 = ((const float4*)x)[i * 2];
            float4 v1 = ((const float4*)x)[i * 2 + 1];
            short8 o;
            o[0] = (short)f2bf(v0.x * dv); o[1] = (short)f2bf(v0.y * dv);
            o[2] = (short)f2bf(v0.z * dv); o[3] = (short)f2bf(v0.w * dv);
            o[4] = (short)f2bf(v1.x * dv); o[5] = (short)f2bf(v1.y * dv);
            o[6] = (short)f2bf(v1.z * dv); o[7] = (short)f2bf(v1.w * dv);
            *(short8*)(xs + (size_t)i * 8) = o;
        }
        return;
    }
    __shared__ int bs[256];
    __shared__ int s[256];
    bs[tid] = (tid < nb) ? bsums[tid] : 0;
    const int i = blockIdx.x * 256 + tid;
    int v = (i < N) ? deg[i] : 0;
    s[tid] = v;
    __syncthreads();
    for (int ofs = 1; ofs < 256; ofs <<= 1) {
        int tb = (tid >= ofs) ? bs[tid - ofs] : 0;
        int tv = (tid >= ofs) ? s[tid - ofs] : 0;
        __syncthreads();
        bs[tid] += tb;
        s[tid] += tv;
        __syncthreads();
    }
    int bbase = (blockIdx.x == 0) ? 0 : bs[blockIdx.x - 1];
    int excl = (tid == 0) ? 0 : s[tid - 1];
    if (i <= N) off[i] = bbase + excl;
}

// Pure scatter: csr[off[dst] + pos] = src.  No atomics.
__global__ void scatter_kernel(const int* __restrict__ src, const int* __restrict__ dst,
                               const int* __restrict__ pos, const int* __restrict__ off,
                               int* __restrict__ csr, int E) {
    int i = blockIdx.x * blockDim.x + threadIdx.x;
    if (i < E) csr[off[dst[i]] + pos[i]] = src[i];
}

// Wave-per-node aggregation over 128-dim bf16 rows, fp32 accumulate.
// Wave = 4 edge-slots x 16 lanes (ushort8 / 16 B per lane); 4 nodes per 256-block.
// MODE 0: out_bf16[n] = bf16( dinv[n] * (self + sum) )
// MODE 1: out_f32[n]  = dinv[n] * (self + sum) + bias
template <int MODE>
__global__ __launch_bounds__(256) void agg_bf16(const unsigned short* __restrict__ hs,
                                                const int* __restrict__ off,
                                                const int* __restrict__ csr,
                                                const float* __restrict__ dinv,
                                                const float* __restrict__ bias,
                                                void* __restrict__ outp, int N) {
    const int wid = threadIdx.x >> 6;
    const int n = blockIdx.x * 4 + wid;
    if (n >= N) return;
    const int lane = threadIdx.x & 63;
    const int lane16 = lane & 15;
    const int slot = lane >> 4;   // 0..3

    float va[8], vb[8], vc[8], vd[8];
#pragma unroll
    for (int j = 0; j < 8; j++) { va[j] = 0.f; vb[j] = 0.f; vc[j] = 0.f; vd[j] = 0.f; }

    if (slot == 0) {  // self loop
        short8 s = *(const short8*)(hs + (size_t)n * 128 + lane16 * 8);
#pragma unroll
        for (int j = 0; j < 8; j++) va[j] = bf2f((unsigned short)s[j]);
    }

    const int e0 = off[n];
    const int e1 = off[n + 1];
    for (int e = e0 + slot; e < e1; e += 16) {
        const int i1 = e + 4, i2 = e + 8, i3 = e + 12;
        const float f1 = (i1 < e1) ? 1.f : 0.f;
        const float f2 = (i2 < e1) ? 1.f : 0.f;
        const float f3 = (i3 < e1) ? 1.f : 0.f;
        const int c1 = min(i1, e1 - 1), c2 = min(i2, e1 - 1), c3 = min(i3, e1 - 1);
        int s0 = csr[e];
        int s1 = csr[c1];
        int s2 = csr[c2];
        int s3 = csr[c3];
        short8 v0 = *(const short8*)(hs + (size_t)s0 * 128 + lane16 * 8);
        short8 v1 = *(const short8*)(hs + (size_t)s1 * 128 + lane16 * 8);
        short8 v2 = *(const short8*)(hs + (size_t)s2 * 128 + lane16 * 8);
        short8 v3 = *(const short8*)(hs + (size_t)s3 * 128 + lane16 * 8);
#pragma unroll
        for (int j = 0; j < 8; j++) va[j] += bf2f((unsigned short)v0[j]);
#pragma unroll
        for (int j = 0; j < 8; j++) vb[j] = fmaf(f1, bf2f((unsigned short)v1[j]), vb[j]);
#pragma unroll
        for (int j = 0; j < 8; j++) vc[j] = fmaf(f2, bf2f((unsigned short)v2[j]), vc[j]);
#pragma unroll
        for (int j = 0; j < 8; j++) vd[j] = fmaf(f3, bf2f((unsigned short)v3[j]), vd[j]);
    }
#pragma unroll
    for (int j = 0; j < 8; j++) va[j] += vb[j] + vc[j] + vd[j];

#pragma unroll
    for (int j = 0; j < 8; j++) va[j] += __shfl_down(va[j], 32);
#pragma unroll
    for (int j = 0; j < 8; j++) va[j] += __shfl_down(va[j], 16);

    if (lane < 16) {
        float dv = dinv[n];
        if (MODE == 0) {
            short8 o;
#pragma unroll
            for (int j = 0; j < 8; j++) o[j] = (short)f2bf(va[j] * dv);
            *(short8*)((unsigned short*)outp + (size_t)n * 128 + lane * 8) = o;
        } else {
            float* op = (float*)outp + (size_t)n * 128 + lane * 8;
            float4 o0, o1;
            o0.x = va[0] * dv + bias[lane * 8 + 0];
            o0.y = va[1] * dv + bias[lane * 8 + 1];
            o0.z = va[2] * dv + bias[lane * 8 + 2];
            o0.w = va[3] * dv + bias[lane * 8 + 3];
            o1.x = va[4] * dv + bias[lane * 8 + 4];
            o1.y = va[5] * dv + bias[lane * 8 + 5];
            o1.z = va[6] * dv + bias[lane * 8 + 6];
            o1.w = va[7] * dv + bias[lane * 8 + 7];
            ((float4*)op)[0] = o0;
            ((float4*)op)[1] = o1;
        }
    }
}

// Fused double GEMM, LDS-fed weights, 64-row macro-tile: hs2 = dinv*(relu(Y@W1+b1)@W2).
// 256 blocks x 512 thr (8 waves), 1 block/CU (160 KiB LDS: w1l 64K + w2l 64K + h2s 32K).
// Prologue stages W1,W2 into FRAGMENT-ORDER LDS from replica (blockIdx&15); in-loop
// weight read = ds_read_b128 at uniform-base + lane*16 (linear, conflict-free), each
// fragment feeds 4 MFMAs (4 row-subtiles). Per iteration (64 rows): 16 Y-loads ->
// 8 ds(B1) + 32 MFMA -> relu/bf16 -> h2s swizzled -> barrier -> 32 ds(h) + 32 ds(B2)
// + 32 MFMA -> *dinv -> store -> barrier. 2 barriers & <=4 iters/block (was 8 & 12.2).
// h2s swizzle: byte ^= (row&7)<<4 -> phase-B 16-row column reads land on 8 distinct
// 16B slots (2-way = free); write side contiguous.
// Frag layouts: A/B m(n)=lane&15, k=q*8+j;  D col=lane&15, row=q*4+reg.
__global__ __launch_bounds__(512, 2) void gemm12(const unsigned short* __restrict__ Y,
                                                 const unsigned short* __restrict__ w1t,
                                                 const float* __restrict__ b1,
                                                 const unsigned short* __restrict__ w2t,
                                                 const float* __restrict__ dinv,
                                                 unsigned short* __restrict__ hs2, int M) {
    __shared__ unsigned short w1l[F_IN * HID];    // 65536 B, fragment-order
    __shared__ unsigned short w2l[HID * F_OUT];   // 65536 B, fragment-order
    __shared__ unsigned short h2s[64 * 256];      // 32768 B, XOR-swizzled

    const int tid = threadIdx.x;
    const int wid = tid >> 6;   // 0..7
    const int lane = tid & 63;
    const int an = lane & 15;
    const int q = lane >> 4;
    const int rep = blockIdx.x & (NREP - 1);

    // ---- stage weights into fragment-order LDS (linear ds_write, spread L2 reads) ----
    {
        const unsigned short* w1r = w1t + (size_t)rep * F_IN * HID;
        const unsigned short* w2r = w2t + (size_t)rep * HID * F_OUT;
        // W1 chunks: id = wid*8 + t*4 + c; lane l holds w1^T[col=wid*32+t*16+(l&15)][k=(l>>4)*8+c*32 ..]
        for (int i = tid; i < 4096; i += 512) {
            const int cw = i >> 9;
            const int t  = (i >> 8) & 1;
            const int c  = (i >> 6) & 3;
            const int l  = i & 63;
            const int col = cw * 32 + t * 16 + (l & 15);
            const int off = col * F_IN + (l >> 4) * 8 + c * 32;
            *(short8*)(w1l + (size_t)i * 8) = *(const short8*)(w1r + off);
        }
        // W2 chunks: id = wid*8 + c; lane l holds w2^T[col=wid*16+(l&15)][k=(l>>4)*8+c*32 ..]
        for (int i = tid; i < 4096; i += 512) {
            const int cw = i >> 9;
            const int c  = (i >> 6) & 7;
            const int l  = i & 63;
            const int colB = cw * 16 + (l & 15);
            const int off = colB * HID + (l >> 4) * 8 + c * 32;
            *(short8*)(w2l + (size_t)i * 8) = *(const short8*)(w2r + off);
        }
    }
    const float bv0 = b1[wid * 32 + an];
    const float bv1 = b1[wid * 32 + 16 + an];
    __syncthreads();

    const int T = (M + 63) >> 6;   // 782 macro-tiles
    for (int t0 = blockIdx.x; t0 < T; t0 += gridDim.x) {
        const int m0 = t0 * 64;

        // ---- Phase A: h2 = relu(Y@W1+b1) -> swizzled LDS (wave: cols [wid*32,+32)) ----
        short8 a[4][4];
#pragma unroll
        for (int s = 0; s < 4; s++) {
            int row = m0 + s * 16 + an;
            if (row >= M) row = M - 1;
            const unsigned short* yp = Y + (size_t)row * F_IN + q * 8;
#pragma unroll
            for (int c = 0; c < 4; c++) a[s][c] = *(const short8*)(yp + c * 32);
        }
        f32x4 acc[4][2];
#pragma unroll
        for (int s = 0; s < 4; s++) {
            acc[s][0] = (f32x4){0.f, 0.f, 0.f, 0.f};
            acc[s][1] = (f32x4){0.f, 0.f, 0.f, 0.f};
        }
#pragma unroll
        for (int c = 0; c < 4; c++) {
            const short8 b0 = *(const short8*)(w1l + ((size_t)((wid * 8 + c) * 64 + lane)) * 8);
            const short8 b1f = *(const short8*)(w1l + ((size_t)((wid * 8 + 4 + c) * 64 + lane)) * 8);
#pragma unroll
            for (int s = 0; s < 4; s++) {
                acc[s][0] = __builtin_amdgcn_mfma_f32_16x16x32_bf16(a[s][c], b0, acc[s][0], 0, 0, 0);
                acc[s][1] = __builtin_amdgcn_mfma_f32_16x16x32_bf16(a[s][c], b1f, acc[s][1], 0, 0, 0);
            }
        }
        {
            const int c0 = wid * 32 + an;
#pragma unroll
            for (int s = 0; s < 4; s++) {
#pragma unroll
                for (int rr = 0; rr < 4; rr++) {
                    const int brow = s * 16 + q * 4 + rr;
                    const int base = brow * 256;
                    const int xr = (brow & 7) << 4;
                    *(unsigned short*)((char*)h2s + (((base + c0) * 2) ^ xr)) =
                        f2bf(fmaxf(acc[s][0][rr] + bv0, 0.f));
                    *(unsigned short*)((char*)h2s + (((base + c0 + 16) * 2) ^ xr)) =
                        f2bf(fmaxf(acc[s][1][rr] + bv1, 0.f));
                }
            }
        }
        __syncthreads();

        // ---- Phase B: hs2 = dinv * (h2 @ W2)  (wave: cols [wid*16,+16), rows all 64) ----
#pragma unroll
        for (int s = 0; s < 4; s++) {
            const int rbase = s * 16 + an;
            const int xr = (rbase & 7) << 4;
            f32x4 accB = {0.f, 0.f, 0.f, 0.f};
#pragma unroll
            for (int c = 0; c < 8; c++) {
                const short8 h = *(const short8*)((const char*)h2s +
                                  (((rbase * 256 + c * 32 + q * 8) * 2) ^ xr));
                const short8 b2f = *(const short8*)(w2l + ((size_t)((wid * 8 + c) * 64 + lane)) * 8);
                accB = __builtin_amdgcn_mfma_f32_16x16x32_bf16(h, b2f, accB, 0, 0, 0);
            }
            const int mbase = m0 + s * 16;
            const float4 dv4 = ((const float4*)dinv)[(mbase >> 2) + q];
            unsigned short* op = hs2 + (size_t)(mbase + q * 4) * F_OUT + wid * 16 + an;
            const float dvs[4] = {dv4.x, dv4.y, dv4.z, dv4.w};
#pragma unroll
            for (int rr = 0; rr < 4; rr++) {
                if (mbase + q * 4 + rr < M) op[rr * F_OUT] = f2bf(accB[rr] * dvs[rr]);
            }
        }
        __syncthreads();
    }
}

extern "C" void kernel_launch(void* const* d_in, const int* in_sizes, int n_in,
                              void* d_out, int out_size, void* d_ws, size_t ws_size,
                              hipStream_t stream) {
    const float* x  = (const float*)d_in[0];
    const int*   ei = (const int*)d_in[1];   // [2,E] int32
    const float* W1 = (const float*)d_in[2];
    const float* b1 = (const float*)d_in[3];
    const float* W2 = (const float*)d_in[4];
    const float* b2 = (const float*)d_in[5];

    const int N = N_NODES;
    const int E = N_EDGES;
    const int* srcp = ei;
    const int* dstp = ei + E;

    char* base = (char*)d_ws;
    size_t o = 0;
    auto alloc = [&](size_t bytes) {
        void* p = base + o;
        o = (o + bytes + 255) & ~(size_t)255;
        return p;
    };
    int*            deg  = (int*)alloc((size_t)N * 4);
    int*            offs = (int*)alloc((size_t)(N + 1) * 4);
    float*          dinv = (float*)alloc((size_t)N * 4);
    int*            bsum = (int*)alloc(256 * 4);
    int*            pos  = (int*)alloc((size_t)E * 4);
    int*            csr  = (int*)alloc((size_t)E * 4);
    unsigned short* xs   = (unsigned short*)alloc((size_t)N * F_IN * 2);  // dinv*x, bf16
    unsigned short* Y    = (unsigned short*)alloc((size_t)N * F_IN * 2);  // A_hat@X, bf16
    unsigned short* w1t  = (unsigned short*)alloc((size_t)NREP * F_IN * HID * 2);
    unsigned short* w2t  = (unsigned short*)alloc((size_t)NREP * HID * F_OUT * 2);
    unsigned short* hs2  = xs;  // xs dead after agg1

    hipMemsetAsync(deg, 0, (size_t)N * 4, stream);

    const int NB  = (N + 256) / 256;           // 196, covers i==N in scan_final
    const int NBX = (N * F_IN / 8 + 255) / 256;
    const int EB  = (E + 255) / 256;
    const int NB1 = (F_IN * HID + 255) / 256;
    const int NB2 = (HID * F_OUT + 255) / 256;

    deg_wt_kernel<<<EB + NB1 + NB2, 256, 0, stream>>>(dstp, deg, pos, E, W1, w1t, W2, w2t, EB, NB1);
    scan_reduce_dinv<<<NB, 256, 0, stream>>>(deg, bsum, dinv, N);
    scan_final_scalex<<<NB + NBX, 256, 0, stream>>>(deg, bsum, offs, N, NB, x, dinv, xs);
    scatter_kernel<<<EB, 256, 0, stream>>>(srcp, dstp, pos, offs, csr, E);

    // layer 1 agg: Y = A_hat@X (bf16 gather)
    agg_bf16<0><<<(N + 3) / 4, 256, 0, stream>>>(xs, offs, csr, dinv, nullptr, Y, N);
    // fused GEMMs: hs2 = dinv * ( relu(Y@W1+b1) @ W2 ), 64-row macro-tiles
    gemm12<<<256, 512, 0, stream>>>(Y, w1t, b1, w2t, dinv, hs2, N);
    // layer 2 agg: out = dinv*(hs2[self]+gather) + b2
    agg_bf16<1><<<(N + 3) / 4, 256, 0, stream>>>(hs2, offs, csr, dinv, b2, d_out, N);
}

// Round 7
// 237.483 us; speedup vs baseline: 1.0975x; 1.0430x over previous
//
#include <hip/hip_runtime.h>
#include <hip/hip_bf16.h>

// 2-layer GCN: out = A_hat @ relu((A_hat@X)@W1 + b1) @ W2 + b2,  A_hat = D^-1/2 (A+I) D^-1/2
// R8-R14 ledger: fused gemm12 pinned at 42-63us across SEVEN structures; every
//   mechanistic theory (latency/TLP, L2 hot-line storm, VGPR spills, barrier
//   granularity) falsified by direct experiment; all pipes <7% busy; visible work
//   arithmetic says ~8-12us. Two surviving hypotheses: (a) the fused two-phase
//   structure itself, (b) large fixed per-dispatch cost.
// R15 DISCRIMINATOR: split into two textbook straight-line GEMMs (one tile per block,
//   no loops, no inter-phase barrier, nothing loop-carried): gemm1 = relu(Y@W1+b1)->h2
//   (bf16 global intermediate), gemm2 = dinv*(h2@W2)->hs2. R13-verified fragment-order
//   weight LDS (64KB, 2 blocks/CU), direct global A-frag loads, 391 blocks x 512thr.
//   (a) true -> each ~8-15us, total ~225-235. (b) true -> total ~285-295, next round
//   merges dispatches instead.

static constexpr int N_NODES = 50000;
static constexpr int N_EDGES = 800000;
static constexpr int F_IN = 128;
static constexpr int HID  = 256;
static constexpr int F_OUT = 128;
static constexpr int NREP = 16;    // weight replicas (L2 spread for staging reads)

typedef __attribute__((ext_vector_type(8))) short short8;   // 8 bf16 raw bits (4 VGPRs)
typedef __attribute__((ext_vector_type(4))) float f32x4;

__device__ __forceinline__ unsigned short f2bf(float f) {   // RNE fp32->bf16
    union { float f; unsigned u; } x; x.f = f;
    unsigned r = x.u + 0x7FFF + ((x.u >> 16) & 1);
    return (unsigned short)(r >> 16);
}
__device__ __forceinline__ float bf2f(unsigned short h) {
    union { unsigned u; float f; } x; x.u = ((unsigned)h) << 16;
    return x.f;
}

// Fused independent prep: deg/pos atomics  |  W1^T x16  |  W2^T x16   (grid-partitioned)
__global__ void deg_wt_kernel(const int* __restrict__ dst, int* __restrict__ deg,
                              int* __restrict__ pos, int E,
                              const float* __restrict__ W1, unsigned short* __restrict__ w1t,
                              const float* __restrict__ W2, unsigned short* __restrict__ w2t,
                              int EB, int NB1) {
    const int b = blockIdx.x;
    if (b < EB) {
        int i = b * 256 + threadIdx.x;
        if (i < E) pos[i] = atomicAdd(&deg[dst[i]], 1);
    } else if (b < EB + NB1) {
        int t = (b - EB) * 256 + threadIdx.x;       // W1: F_IN rows x HID cols -> w1t[HID][F_IN]
        if (t < F_IN * HID) {
            int n = t / F_IN, k = t - n * F_IN;
            unsigned short v = f2bf(W1[(size_t)k * HID + n]);
#pragma unroll
            for (int r = 0; r < NREP; r++) w1t[(size_t)r * F_IN * HID + t] = v;
        }
    } else {
        int t = (b - EB - NB1) * 256 + threadIdx.x; // W2: HID rows x F_OUT cols -> w2t[F_OUT][HID]
        if (t < HID * F_OUT) {
            int n = t / HID, k = t - n * HID;
            unsigned short v = f2bf(W2[(size_t)k * F_OUT + n]);
#pragma unroll
            for (int r = 0; r < NREP; r++) w2t[(size_t)r * HID * F_OUT + t] = v;
        }
    }
}

// Fused: per-block sum of deg -> bsums, plus dinv[i] = rsqrt(deg+1).
__global__ __launch_bounds__(256) void scan_reduce_dinv(const int* __restrict__ deg,
                                                        int* __restrict__ bsums,
                                                        float* __restrict__ dinv, int N) {
    int i = blockIdx.x * 256 + threadIdx.x;
    int v = (i < N) ? deg[i] : 0;
    if (i < N) dinv[i] = rsqrtf((float)(v + 1));   // +1 = self loop
#pragma unroll
    for (int ofs = 32; ofs > 0; ofs >>= 1) v += __shfl_down(v, ofs);
    __shared__ int ws[4];
    if ((threadIdx.x & 63) == 0) ws[threadIdx.x >> 6] = v;
    __syncthreads();
    if (threadIdx.x == 0) bsums[blockIdx.x] = ws[0] + ws[1] + ws[2] + ws[3];
}

// Fused: blocks [0,nb): redundant LDS scan of bsums + intra-block scan of deg -> off;
// blocks [nb, ...): xs = bf16(dinv * x)  (dinv ready since scan_reduce_dinv).
__global__ __launch_bounds__(256) void scan_final_scalex(const int* __restrict__ deg,
                                                         const int* __restrict__ bsums,
                                                         int* __restrict__ off, int N, int nb,
                                                         const float* __restrict__ x,
                                                         const float* __restrict__ dinv,
                                                         unsigned short* __restrict__ xs) {
    const int tid = threadIdx.x;
    if ((int)blockIdx.x >= nb) {   // scalex partition
        int i = (blockIdx.x - nb) * 256 + tid;     // one thread per 8 elems
        if (i < N_NODES * F_IN / 8) {
            float dv = dinv[i >> 4];
            float4 v0 = ((const float4*)x)[i * 2];
            float4 v1 = ((const float4*)x)[i * 2 + 1];
            short8 o;
            o[0] = (short)f2bf(v0.x * dv); o[1] = (short)f2bf(v0.y * dv);
            o[2] = (short)f2bf(v0.z * dv); o[3] = (short)f2bf(v0.w * dv);
            o[4] = (short)f2bf(v1.x * dv); o[5] = (short)f2bf(v1.y * dv);
            o[6] = (short)f2bf(v1.z * dv); o[7] = (short)f2bf(v1.w * dv);
            *(short8*)(xs + (size_t)i * 8) = o;
        }
        return;
    }
    __shared__ int bs[256];
    __shared__ int s[256];
    bs[tid] = (tid < nb) ? bsums[tid] : 0;
    const int i = blockIdx.x * 256 + tid;
    int v = (i < N) ? deg[i] : 0;
    s[tid] = v;
    __syncthreads();
    for (int ofs = 1; ofs < 256; ofs <<= 1) {
        int tb = (tid >= ofs) ? bs[tid - ofs] : 0;
        int tv = (tid >= ofs) ? s[tid - ofs] : 0;
        __syncthreads();
        bs[tid] += tb;
        s[tid] += tv;
        __syncthreads();
    }
    int bbase = (blockIdx.x == 0) ? 0 : bs[blockIdx.x - 1];
    int excl = (tid == 0) ? 0 : s[tid - 1];
    if (i <= N) off[i] = bbase + excl;
}

// Pure scatter: csr[off[dst] + pos] = src.  No atomics.
__global__ void scatter_kernel(const int* __restrict__ src, const int* __restrict__ dst,
                               const int* __restrict__ pos, const int* __restrict__ off,
                               int* __restrict__ csr, int E) {
    int i = blockIdx.x * blockDim.x + threadIdx.x;
    if (i < E) csr[off[dst[i]] + pos[i]] = src[i];
}

// Wave-per-node aggregation over 128-dim bf16 rows, fp32 accumulate.
// Wave = 4 edge-slots x 16 lanes (ushort8 / 16 B per lane); 4 nodes per 256-block.
// MODE 0: out_bf16[n] = bf16( dinv[n] * (self + sum) )
// MODE 1: out_f32[n]  = dinv[n] * (self + sum) + bias
template <int MODE>
__global__ __launch_bounds__(256) void agg_bf16(const unsigned short* __restrict__ hs,
                                                const int* __restrict__ off,
                                                const int* __restrict__ csr,
                                                const float* __restrict__ dinv,
                                                const float* __restrict__ bias,
                                                void* __restrict__ outp, int N) {
    const int wid = threadIdx.x >> 6;
    const int n = blockIdx.x * 4 + wid;
    if (n >= N) return;
    const int lane = threadIdx.x & 63;
    const int lane16 = lane & 15;
    const int slot = lane >> 4;   // 0..3

    float va[8], vb[8], vc[8], vd[8];
#pragma unroll
    for (int j = 0; j < 8; j++) { va[j] = 0.f; vb[j] = 0.f; vc[j] = 0.f; vd[j] = 0.f; }

    if (slot == 0) {  // self loop
        short8 s = *(const short8*)(hs + (size_t)n * 128 + lane16 * 8);
#pragma unroll
        for (int j = 0; j < 8; j++) va[j] = bf2f((unsigned short)s[j]);
    }

    const int e0 = off[n];
    const int e1 = off[n + 1];
    for (int e = e0 + slot; e < e1; e += 16) {
        const int i1 = e + 4, i2 = e + 8, i3 = e + 12;
        const float f1 = (i1 < e1) ? 1.f : 0.f;
        const float f2 = (i2 < e1) ? 1.f : 0.f;
        const float f3 = (i3 < e1) ? 1.f : 0.f;
        const int c1 = min(i1, e1 - 1), c2 = min(i2, e1 - 1), c3 = min(i3, e1 - 1);
        int s0 = csr[e];
        int s1 = csr[c1];
        int s2 = csr[c2];
        int s3 = csr[c3];
        short8 v0 = *(const short8*)(hs + (size_t)s0 * 128 + lane16 * 8);
        short8 v1 = *(const short8*)(hs + (size_t)s1 * 128 + lane16 * 8);
        short8 v2 = *(const short8*)(hs + (size_t)s2 * 128 + lane16 * 8);
        short8 v3 = *(const short8*)(hs + (size_t)s3 * 128 + lane16 * 8);
#pragma unroll
        for (int j = 0; j < 8; j++) va[j] += bf2f((unsigned short)v0[j]);
#pragma unroll
        for (int j = 0; j < 8; j++) vb[j] = fmaf(f1, bf2f((unsigned short)v1[j]), vb[j]);
#pragma unroll
        for (int j = 0; j < 8; j++) vc[j] = fmaf(f2, bf2f((unsigned short)v2[j]), vc[j]);
#pragma unroll
        for (int j = 0; j < 8; j++) vd[j] = fmaf(f3, bf2f((unsigned short)v3[j]), vd[j]);
    }
#pragma unroll
    for (int j = 0; j < 8; j++) va[j] += vb[j] + vc[j] + vd[j];

#pragma unroll
    for (int j = 0; j < 8; j++) va[j] += __shfl_down(va[j], 32);
#pragma unroll
    for (int j = 0; j < 8; j++) va[j] += __shfl_down(va[j], 16);

    if (lane < 16) {
        float dv = dinv[n];
        if (MODE == 0) {
            short8 o;
#pragma unroll
            for (int j = 0; j < 8; j++) o[j] = (short)f2bf(va[j] * dv);
            *(short8*)((unsigned short*)outp + (size_t)n * 128 + lane * 8) = o;
        } else {
            float* op = (float*)outp + (size_t)n * 128 + lane * 8;
            float4 o0, o1;
            o0.x = va[0] * dv + bias[lane * 8 + 0];
            o0.y = va[1] * dv + bias[lane * 8 + 1];
            o0.z = va[2] * dv + bias[lane * 8 + 2];
            o0.w = va[3] * dv + bias[lane * 8 + 3];
            o1.x = va[4] * dv + bias[lane * 8 + 4];
            o1.y = va[5] * dv + bias[lane * 8 + 5];
            o1.z = va[6] * dv + bias[lane * 8 + 6];
            o1.w = va[7] * dv + bias[lane * 8 + 7];
            ((float4*)op)[0] = o0;
            ((float4*)op)[1] = o1;
        }
    }
}

// GEMM1 (straight-line): h2[m, 0:256] = relu(Y[m, 0:128] @ W1 + b1), bf16 out.
// 391 blocks x 512 thr (8 waves); block tile = 128 rows; wave = 16 rows x 256 cols.
// W1 in fragment-order LDS (R13-verified mapping, 64 KB, 2 blocks/CU). A-frags loaded
// direct from global (4 x short8 per lane). 16 col-tiles x 4 k-frags = 64 ds + 64 MFMA.
// No loops over tiles, no inter-phase barrier, nothing loop-carried.
__global__ __launch_bounds__(512, 2) void gemm1(const unsigned short* __restrict__ Y,
                                                const unsigned short* __restrict__ w1t,
                                                const float* __restrict__ b1,
                                                unsigned short* __restrict__ h2, int M) {
    __shared__ unsigned short w1l[F_IN * HID];   // 65536 B, fragment-order

    const int tid = threadIdx.x;
    const int wid = tid >> 6;
    const int lane = tid & 63;
    const int an = lane & 15;
    const int q = lane >> 4;
    const int rep = blockIdx.x & (NREP - 1);

    {   // stage W1 replica -> fragment-order LDS (R13-verified)
        const unsigned short* w1r = w1t + (size_t)rep * F_IN * HID;
        for (int i = tid; i < 4096; i += 512) {
            const int cw = i >> 9;
            const int t  = (i >> 8) & 1;
            const int c  = (i >> 6) & 3;
            const int l  = i & 63;
            const int col = cw * 32 + t * 16 + (l & 15);
            const int off = col * F_IN + (l >> 4) * 8 + c * 32;
            *(short8*)(w1l + (size_t)i * 8) = *(const short8*)(w1r + off);
        }
    }
    float bvs[16];
#pragma unroll
    for (int t = 0; t < 16; t++) bvs[t] = b1[t * 16 + an];
    __syncthreads();

    const int m0 = blockIdx.x * 128 + wid * 16;
    int row = m0 + an;
    if (row >= M) row = M - 1;
    short8 a[4];
    {
        const unsigned short* yp = Y + (size_t)row * F_IN + q * 8;
#pragma unroll
        for (int c = 0; c < 4; c++) a[c] = *(const short8*)(yp + c * 32);
    }
    const int mb = m0 + q * 4;
#pragma unroll
    for (int tt = 0; tt < 16; tt++) {
        f32x4 acc = {0.f, 0.f, 0.f, 0.f};
#pragma unroll
        for (int c = 0; c < 4; c++) {
            const short8 b = *(const short8*)(w1l +
                              ((size_t)(((tt >> 1) * 8 + (tt & 1) * 4 + c) * 64 + lane)) * 8);
            acc = __builtin_amdgcn_mfma_f32_16x16x32_bf16(a[c], b, acc, 0, 0, 0);
        }
        const int col = tt * 16 + an;
#pragma unroll
        for (int rr = 0; rr < 4; rr++) {
            const int m = mb + rr;
            if (m < M) h2[(size_t)m * HID + col] = f2bf(fmaxf(acc[rr] + bvs[tt], 0.f));
        }
    }
}

// GEMM2 (straight-line): hs2[m, 0:128] = dinv[m] * (h2[m, 0:256] @ W2), bf16 out.
// Same shape as gemm1: 391 blocks x 512 thr, wave = 16 rows x 128 cols,
// 8 col-tiles x 8 k-frags = 64 ds + 64 MFMA. W2 fragment-order LDS (R13-verified).
__global__ __launch_bounds__(512, 2) void gemm2(const unsigned short* __restrict__ h2,
                                                const unsigned short* __restrict__ w2t,
                                                const float* __restrict__ dinv,
                                                unsigned short* __restrict__ hs2, int M) {
    __shared__ unsigned short w2l[HID * F_OUT];   // 65536 B, fragment-order

    const int tid = threadIdx.x;
    const int wid = tid >> 6;
    const int lane = tid & 63;
    const int an = lane & 15;
    const int q = lane >> 4;
    const int rep = blockIdx.x & (NREP - 1);

    {   // stage W2 replica -> fragment-order LDS (R13-verified)
        const unsigned short* w2r = w2t + (size_t)rep * HID * F_OUT;
        for (int i = tid; i < 4096; i += 512) {
            const int cw = i >> 9;
            const int c  = (i >> 6) & 7;
            const int l  = i & 63;
            const int colB = cw * 16 + (l & 15);
            const int off = colB * HID + (l >> 4) * 8 + c * 32;
            *(short8*)(w2l + (size_t)i * 8) = *(const short8*)(w2r + off);
        }
    }
    __syncthreads();

    const int m0 = blockIdx.x * 128 + wid * 16;
    int row = m0 + an;
    if (row >= M) row = M - 1;
    short8 a[8];
    {
        const unsigned short* hp = h2 + (size_t)row * HID + q * 8;
#pragma unroll
        for (int c = 0; c < 8; c++) a[c] = *(const short8*)(hp + c * 32);
    }
    const int mb = m0 + q * 4;
    float dv[4];
#pragma unroll
    for (int rr = 0; rr < 4; rr++) dv[rr] = (mb + rr < M) ? dinv[mb + rr] : 0.f;
#pragma unroll
    for (int tt = 0; tt < 8; tt++) {
        f32x4 acc = {0.f, 0.f, 0.f, 0.f};
#pragma unroll
        for (int c = 0; c < 8; c++) {
            const short8 b = *(const short8*)(w2l + ((size_t)((tt * 8 + c) * 64 + lane)) * 8);
            acc = __builtin_amdgcn_mfma_f32_16x16x32_bf16(a[c], b, acc, 0, 0, 0);
        }
        const int col = tt * 16 + an;
#pragma unroll
        for (int rr = 0; rr < 4; rr++) {
            const int m = mb + rr;
            if (m < M) hs2[(size_t)m * F_OUT + col] = f2bf(acc[rr] * dv[rr]);
        }
    }
}

extern "C" void kernel_launch(void* const* d_in, const int* in_sizes, int n_in,
                              void* d_out, int out_size, void* d_ws, size_t ws_size,
                              hipStream_t stream) {
    const float* x  = (const float*)d_in[0];
    const int*   ei = (const int*)d_in[1];   // [2,E] int32
    const float* W1 = (const float*)d_in[2];
    const float* b1 = (const float*)d_in[3];
    const float* W2 = (const float*)d_in[4];
    const float* b2 = (const float*)d_in[5];

    const int N = N_NODES;
    const int E = N_EDGES;
    const int* srcp = ei;
    const int* dstp = ei + E;

    char* base = (char*)d_ws;
    size_t o = 0;
    auto alloc = [&](size_t bytes) {
        void* p = base + o;
        o = (o + bytes + 255) & ~(size_t)255;
        return p;
    };
    int*            deg  = (int*)alloc((size_t)N * 4);
    int*            offs = (int*)alloc((size_t)(N + 1) * 4);
    float*          dinv = (float*)alloc((size_t)N * 4);
    int*            bsum = (int*)alloc(256 * 4);
    int*            pos  = (int*)alloc((size_t)E * 4);
    int*            csr  = (int*)alloc((size_t)E * 4);
    unsigned short* xs   = (unsigned short*)alloc((size_t)N * F_IN * 2);  // dinv*x, bf16
    unsigned short* Y    = (unsigned short*)alloc((size_t)N * F_IN * 2);  // A_hat@X, bf16
    unsigned short* h2   = (unsigned short*)alloc((size_t)N * HID * 2);   // relu(Y@W1+b1), bf16
    unsigned short* w1t  = (unsigned short*)alloc((size_t)NREP * F_IN * HID * 2);
    unsigned short* w2t  = (unsigned short*)alloc((size_t)NREP * HID * F_OUT * 2);
    unsigned short* hs2  = xs;  // xs dead after agg1

    hipMemsetAsync(deg, 0, (size_t)N * 4, stream);

    const int NB  = (N + 256) / 256;           // 196, covers i==N in scan_final
    const int NBX = (N * F_IN / 8 + 255) / 256;
    const int EB  = (E + 255) / 256;
    const int NB1 = (F_IN * HID + 255) / 256;
    const int NB2 = (HID * F_OUT + 255) / 256;
    const int GB  = (N + 127) / 128;           // 391 GEMM blocks

    deg_wt_kernel<<<EB + NB1 + NB2, 256, 0, stream>>>(dstp, deg, pos, E, W1, w1t, W2, w2t, EB, NB1);
    scan_reduce_dinv<<<NB, 256, 0, stream>>>(deg, bsum, dinv, N);
    scan_final_scalex<<<NB + NBX, 256, 0, stream>>>(deg, bsum, offs, N, NB, x, dinv, xs);
    scatter_kernel<<<EB, 256, 0, stream>>>(srcp, dstp, pos, offs, csr, E);

    // layer 1 agg: Y = A_hat@X (bf16 gather)
    agg_bf16<0><<<(N + 3) / 4, 256, 0, stream>>>(xs, offs, csr, dinv, nullptr, Y, N);
    // split GEMMs (R15 discriminator): h2 = relu(Y@W1+b1);  hs2 = dinv*(h2@W2)
    gemm1<<<GB, 512, 0, stream>>>(Y, w1t, b1, h2, N);
    gemm2<<<GB, 512, 0, stream>>>(h2, w2t, dinv, hs2, N);
    // layer 2 agg: out = dinv*(hs2[self]+gather) + b2
    agg_bf16<1><<<(N + 3) / 4, 256, 0, stream>>>(hs2, offs, csr, dinv, b2, d_out, N);
}